// Round 1
// baseline (1199.298 us; speedup 1.0000x reference)
//
#include <hip/hip_runtime.h>

typedef _Float16 f16;
typedef _Float16 f16x8 __attribute__((ext_vector_type(8)));
typedef _Float16 f16x4 __attribute__((ext_vector_type(4)));
typedef float    f32x4 __attribute__((ext_vector_type(4)));

#define GLDS(gp, lp) __builtin_amdgcn_global_load_lds( \
    (const __attribute__((address_space(1))) void*)(gp), \
    (__attribute__((address_space(3))) void*)(lp), 16, 0, 0)

// ---------------------------------------------------------------------------
// C[M,N] = A[M,K] * B[N,K]^T  (+bias, +relu)   A,B fp16 row-major, fp32 accum
// 128x128 tile, BK=32, 256 threads (4 waves, 2x2 of 64x64), mfma 16x16x32 f16
// ---------------------------------------------------------------------------
template<typename OUT_T, bool BIAS, bool RELU>
__global__ __launch_bounds__(256)
void gemm_bt(const f16* __restrict__ A, const f16* __restrict__ Bm,
             OUT_T* __restrict__ C, const float* __restrict__ bias,
             int M, int N, int K, long sA, long sB, long sC)
{
    __shared__ alignas(16) f16 As[128 * 32];
    __shared__ alignas(16) f16 Bs[128 * 32];

    const int z = blockIdx.z;
    A  += (long)z * sA;
    Bm += (long)z * sB;
    C  += (long)z * sC;

    const int tid  = threadIdx.x;
    const int wid  = tid >> 6;
    const int lane = tid & 63;
    const int m0 = blockIdx.y * 128;
    const int n0 = blockIdx.x * 128;
    const int wm = (wid >> 1) * 64;
    const int wn = (wid & 1) * 64;

    // staging: chunk c in [0,512): row = c>>2, 8-elem segment = c&3.
    // LDS dst = chunk*16B; per-wave-uniform base, lane scatters +lane*16.
    const int r0s = tid >> 2;
    const int sgs = (tid & 3) * 8;
    const int r1s = (tid + 256) >> 2;
    const f16* ag0 = A  + (long)(m0 + r0s) * K + sgs;
    const f16* ag1 = A  + (long)(m0 + r1s) * K + sgs;
    const f16* bg0 = Bm + (long)(n0 + r0s) * K + sgs;
    const f16* bg1 = Bm + (long)(n0 + r1s) * K + sgs;
    f16* asl0 = As + (wid * 64) * 8;          // uniform per wave
    f16* asl1 = As + (256 + wid * 64) * 8;
    f16* bsl0 = Bs + (wid * 64) * 8;
    f16* bsl1 = Bs + (256 + wid * 64) * 8;

    const int frow = lane & 15;       // m (or n) within 16-tile
    const int fk   = (lane >> 4) * 8; // k offset within BK=32

    f32x4 acc[4][4];
#pragma unroll
    for (int i = 0; i < 4; ++i)
#pragma unroll
        for (int j = 0; j < 4; ++j) acc[i][j] = (f32x4){0.f, 0.f, 0.f, 0.f};

    for (int kt = 0; kt < K; kt += 32) {
        GLDS(ag0 + kt, asl0);
        GLDS(ag1 + kt, asl1);
        GLDS(bg0 + kt, bsl0);
        GLDS(bg1 + kt, bsl1);
        __syncthreads();

        f16x8 af[4], bf[4];
#pragma unroll
        for (int mi = 0; mi < 4; ++mi)
            af[mi] = *(const f16x8*)(As + (wm + mi * 16 + frow) * 32 + fk);
#pragma unroll
        for (int ni = 0; ni < 4; ++ni)
            bf[ni] = *(const f16x8*)(Bs + (wn + ni * 16 + frow) * 32 + fk);
#pragma unroll
        for (int mi = 0; mi < 4; ++mi)
#pragma unroll
            for (int ni = 0; ni < 4; ++ni)
                acc[mi][ni] = __builtin_amdgcn_mfma_f32_16x16x32_f16(
                    af[mi], bf[ni], acc[mi][ni], 0, 0, 0);
        __syncthreads();
    }

    // C/D layout (16x16): col = lane&15, row = (lane>>4)*4 + reg  [m89/m91]
    const int er = (lane >> 4) * 4;
    const int ec = lane & 15;
#pragma unroll
    for (int ni = 0; ni < 4; ++ni) {
        const int gc = n0 + wn + ni * 16 + ec;
        const float bv = BIAS ? bias[gc] : 0.0f;
#pragma unroll
        for (int mi = 0; mi < 4; ++mi) {
#pragma unroll
            for (int r = 0; r < 4; ++r) {
                const int gr = m0 + wm + mi * 16 + er + r;
                float v = acc[mi][ni][r] + bv;
                if (RELU) v = fmaxf(v, 0.0f);
                C[(long)gr * N + gc] = (OUT_T)v;
            }
        }
    }
}

// ---------------------------------------------------------------------------
__global__ __launch_bounds__(256)
void cast_f32_f16(const float* __restrict__ X, f16* __restrict__ Y)
{
    const long i = ((long)blockIdx.x * 256 + threadIdx.x) * 8;
    float4 a = *(const float4*)(X + i);
    float4 b = *(const float4*)(X + i + 4);
    f16x8 h = {(f16)a.x, (f16)a.y, (f16)a.z, (f16)a.w,
               (f16)b.x, (f16)b.y, (f16)b.z, (f16)b.w};
    *(f16x8*)(Y + i) = h;
}

// fp32 [2048 x 1024] per batch  ->  fp16 [1024 x 2048] (transposed)
__global__ __launch_bounds__(256)
void transpose_cast(const float* __restrict__ X, f16* __restrict__ Y)
{
    __shared__ f16 t[64][72];
    const float* Xb = X + (long)blockIdx.z * (2048L * 1024);
    f16* Yb = Y + (long)blockIdx.z * (1024L * 2048);
    const int r0 = blockIdx.y * 64;
    const int c0 = blockIdx.x * 64;
    const int tid = threadIdx.x;
    const int tr = tid >> 4;
    const int tc = (tid & 15) * 4;
#pragma unroll
    for (int rr = 0; rr < 64; rr += 16) {
        float4 v = *(const float4*)(Xb + (long)(r0 + tr + rr) * 1024 + c0 + tc);
        f16x4 h = {(f16)v.x, (f16)v.y, (f16)v.z, (f16)v.w};
        *(f16x4*)&t[tr + rr][tc] = h;
    }
    __syncthreads();
#pragma unroll
    for (int rr = 0; rr < 64; rr += 16) {
        const int orow = tr + rr;
        f16x4 o = {t[tc + 0][orow], t[tc + 1][orow], t[tc + 2][orow], t[tc + 3][orow]};
        *(f16x4*)(Yb + (long)(c0 + orow) * 2048 + r0 + tc) = o;
    }
}

// rowwise softmax over 2048 fp32 -> fp16
__global__ __launch_bounds__(256)
void softmax_p(const float* __restrict__ S, f16* __restrict__ P)
{
    const long row = blockIdx.x;
    const float* s = S + row * 2048;
    f16* p = P + row * 2048;
    const int tid = threadIdx.x;
    const int wid = tid >> 6, lane = tid & 63;

    float4 a = *(const float4*)(s + tid * 8);
    float4 b = *(const float4*)(s + tid * 8 + 4);
    float v[8] = {a.x, a.y, a.z, a.w, b.x, b.y, b.z, b.w};

    float m = v[0];
#pragma unroll
    for (int j = 1; j < 8; ++j) m = fmaxf(m, v[j]);
#pragma unroll
    for (int off = 32; off > 0; off >>= 1) m = fmaxf(m, __shfl_xor(m, off, 64));

    __shared__ float red[8];
    if (lane == 0) red[wid] = m;
    __syncthreads();
    m = fmaxf(fmaxf(red[0], red[1]), fmaxf(red[2], red[3]));

    float sum = 0.f;
#pragma unroll
    for (int j = 0; j < 8; ++j) { v[j] = __expf(v[j] - m); sum += v[j]; }
#pragma unroll
    for (int off = 32; off > 0; off >>= 1) sum += __shfl_xor(sum, off, 64);
    if (lane == 0) red[4 + wid] = sum;
    __syncthreads();
    sum = red[4] + red[5] + red[6] + red[7];

    const float inv = 1.0f / sum;
    f16x8 h = {(f16)(v[0] * inv), (f16)(v[1] * inv), (f16)(v[2] * inv), (f16)(v[3] * inv),
               (f16)(v[4] * inv), (f16)(v[5] * inv), (f16)(v[6] * inv), (f16)(v[7] * inv)};
    *(f16x8*)(p + tid * 8) = h;
}

// ---------------------------------------------------------------------------
extern "C" void kernel_launch(void* const* d_in, const int* in_sizes, int n_in,
                              void* d_out, int out_size, void* d_ws, size_t ws_size,
                              hipStream_t stream)
{
    const float* proj_p = (const float*)d_in[0];  // [16,2048,1024]
    const float* proj_q = (const float*)d_in[1];  // [16,2048,1024]
    const float* W      = (const float*)d_in[2];  // [1024,1024]
    const float* bias   = (const float*)d_in[3];  // [1024]
    float* out = (float*)d_out;

    constexpr long Bc = 16, L = 2048, H = 1024, NB = 4;
    constexpr long nPQ = Bc * L * H;              // 33,554,432 elements

    char* ws = (char*)d_ws;
    f16*   pB  = (f16*)(ws + 0L);                 // 67,108,864 B
    f16*   qB  = (f16*)(ws + 67108864L);          // 67,108,864 B
    f16*   qBt = (f16*)(ws + 134217728L);         // 67,108,864 B  [B][H][L]
    f16*   tQ  = (f16*)(ws + 201326592L);         // 67,108,864 B
    f16*   aV  = (f16*)(ws + 268435456L);         // 67,108,864 B
    f16*   Wb  = (f16*)(ws + 335544320L);         //  2,097,152 B
    float* S   = (float*)(ws + 337641472L);       // 67,108,864 B (4 batches fp32)
    f16*   P   = (f16*)(ws + 404750336L);         // 33,554,432 B (4 batches fp16)
    // total ws use: 438,304,768 B

    cast_f32_f16<<<nPQ / (256 * 8), 256, 0, stream>>>(proj_p, pB);
    cast_f32_f16<<<nPQ / (256 * 8), 256, 0, stream>>>(proj_q, qB);
    cast_f32_f16<<<(H * H) / (256 * 8), 256, 0, stream>>>(W, Wb);
    transpose_cast<<<dim3(16, 32, 16), 256, 0, stream>>>(proj_q, qBt);

    // G1: tQ[b,q,o] = qB[b,q,:] . Wb[o,:] + bias[o]
    gemm_bt<f16, true, false><<<dim3(H / 128, (Bc * L) / 128, 1), 256, 0, stream>>>(
        qB, Wb, tQ, bias, (int)(Bc * L), (int)H, (int)H, 0, 0, 0);

    for (int c = 0; c < 4; ++c) {
        const long boff = (long)c * NB * L * H;
        // G2: S[p,q] = pB[p,:] . tQ[q,:]   (fp32 out)
        gemm_bt<float, false, false><<<dim3(L / 128, L / 128, NB), 256, 0, stream>>>(
            pB + boff, tQ + boff, S, nullptr, (int)L, (int)L, (int)H,
            L * H, L * H, L * L);
        // softmax rows -> P fp16
        softmax_p<<<NB * L, 256, 0, stream>>>(S, P);
        // G3: aV[p,h] = P[p,:] . qBt[h,:]
        gemm_bt<f16, false, false><<<dim3(H / 128, L / 128, NB), 256, 0, stream>>>(
            P, qBt + (long)c * NB * H * L, aV + boff, nullptr, (int)L, (int)H, (int)L,
            L * L, H * L, L * H);
    }

    // G4: out = relu(aV . Wb^T + bias)  (fp32 out)
    gemm_bt<float, false, true><<<dim3(H / 128, (Bc * L) / 128, 1), 256, 0, stream>>>(
        aV, Wb, out, bias, (int)(Bc * L), (int)H, (int)H, 0, 0, 0);
}

// Round 2
// 1099.482 us; speedup vs baseline: 1.0908x; 1.0908x over previous
//
#include <hip/hip_runtime.h>

typedef _Float16 f16;
typedef _Float16 f16x8 __attribute__((ext_vector_type(8)));
typedef _Float16 f16x4 __attribute__((ext_vector_type(4)));
typedef float    f32x16 __attribute__((ext_vector_type(16)));

#define GLDS(gp, lp) __builtin_amdgcn_global_load_lds( \
    (const __attribute__((address_space(1))) void*)(gp), \
    (__attribute__((address_space(3))) void*)(lp), 16, 0, 0)

// ---------------------------------------------------------------------------
// C[M,N] = A[M,K] * B[N,K]^T  (+bias, +relu)   A,B fp16 row-major, fp32 accum
// 128x128 tile, BK=32, 256 threads (4 waves, 2x2 of 64x64), mfma 32x32x16 f16
// LDS k-segment XOR-swizzled by (row>>1)&3 to kill ds_read_b128 bank conflicts.
// Block remap: same-A-row-tile blocks -> same XCD (dispatch id mod 8).
// ---------------------------------------------------------------------------
template<typename OUT_T, bool BIAS, bool RELU>
__global__ __launch_bounds__(256)
void gemm_bt(const f16* __restrict__ A, const f16* __restrict__ Bm,
             OUT_T* __restrict__ C, const float* __restrict__ bias,
             int M, int N, int K, long sA, long sB, long sC)
{
    __shared__ alignas(16) f16 As[128 * 32];
    __shared__ alignas(16) f16 Bs[128 * 32];

    int bx = blockIdx.x, by = blockIdx.y;
    {   // XCD-locality remap (gx*8 and gy%8 assumed to divide; true for all uses)
        const int gx = gridDim.x;
        const int l = by * gx + bx;
        const int W = gx * 8;
        const int ygrp = l / W;
        const int rem = l - ygrp * W;
        bx = rem >> 3;
        by = ygrp * 8 + (rem & 7);
    }

    const int z = blockIdx.z;
    A  += (long)z * sA;
    Bm += (long)z * sB;
    C  += (long)z * sC;

    const int tid  = threadIdx.x;
    const int wid  = tid >> 6;
    const int lane = tid & 63;
    const int m0 = by * 128;
    const int n0 = bx * 128;
    const int wm = (wid >> 1) * 64;
    const int wn = (wid & 1) * 64;

    // staging: chunk c in [0,512): row r = c>>2, LDS slot s = c&3.
    // source k-segment g = s ^ ((r>>1)&3)  (XOR swizzle, (r+64) gives same swz)
    const int r0s  = tid >> 2;
    const int sgsw = ((tid & 3) ^ ((tid >> 3) & 3)) * 8;
    const f16* ag0 = A  + (long)(m0 + r0s) * K + sgsw;
    const f16* ag1 = A  + (long)(m0 + r0s + 64) * K + sgsw;
    const f16* bg0 = Bm + (long)(n0 + r0s) * K + sgsw;
    const f16* bg1 = Bm + (long)(n0 + r0s + 64) * K + sgsw;
    f16* asl0 = As + (wid * 64) * 8;          // wave-uniform base
    f16* asl1 = As + (256 + wid * 64) * 8;
    f16* bsl0 = Bs + (wid * 64) * 8;
    f16* bsl1 = Bs + (256 + wid * 64) * 8;

    // fragment addressing (32x32x16: m/n = lane&31, k-half = lane>>5)
    const int lr   = lane & 31;
    const int lh   = lane >> 5;
    const int swz  = (lr >> 1) & 3;
    const int off0 = ((lh ^ swz)) * 8;        // ks=0: G = lh
    const int off1 = ((lh ^ swz) ^ 2) * 8;    // ks=1: G = 2+lh

    f32x16 acc[2][2];
#pragma unroll
    for (int i = 0; i < 2; ++i)
#pragma unroll
        for (int j = 0; j < 2; ++j)
#pragma unroll
            for (int r = 0; r < 16; ++r) acc[i][j][r] = 0.f;

    for (int kt = 0; kt < K; kt += 32) {
        GLDS(ag0 + kt, asl0);
        GLDS(ag1 + kt, asl1);
        GLDS(bg0 + kt, bsl0);
        GLDS(bg1 + kt, bsl1);
        __syncthreads();

        const f16* ar0 = As + (wm + lr) * 32;
        const f16* ar1 = As + (wm + 32 + lr) * 32;
        const f16* br0 = Bs + (wn + lr) * 32;
        const f16* br1 = Bs + (wn + 32 + lr) * 32;
        f16x8 af[2][2], bf[2][2];
        af[0][0] = *(const f16x8*)(ar0 + off0);
        af[0][1] = *(const f16x8*)(ar0 + off1);
        af[1][0] = *(const f16x8*)(ar1 + off0);
        af[1][1] = *(const f16x8*)(ar1 + off1);
        bf[0][0] = *(const f16x8*)(br0 + off0);
        bf[0][1] = *(const f16x8*)(br0 + off1);
        bf[1][0] = *(const f16x8*)(br1 + off0);
        bf[1][1] = *(const f16x8*)(br1 + off1);

#pragma unroll
        for (int ks = 0; ks < 2; ++ks)
#pragma unroll
            for (int mi = 0; mi < 2; ++mi)
#pragma unroll
                for (int ni = 0; ni < 2; ++ni)
                    acc[mi][ni] = __builtin_amdgcn_mfma_f32_32x32x16_f16(
                        af[mi][ks], bf[ni][ks], acc[mi][ni], 0, 0, 0);
        __syncthreads();
    }

    // C/D layout (32x32): col = lane&31, row = (reg&3) + 8*(reg>>2) + 4*(lane>>5)
    const int ec = lr;
#pragma unroll
    for (int ni = 0; ni < 2; ++ni) {
        const int gc = n0 + wn + ni * 32 + ec;
        const float bv = BIAS ? bias[gc] : 0.0f;
#pragma unroll
        for (int mi = 0; mi < 2; ++mi) {
#pragma unroll
            for (int r = 0; r < 16; ++r) {
                const int row = (r & 3) + 8 * (r >> 2) + 4 * lh;
                const int gr = m0 + wm + mi * 32 + row;
                float v = acc[mi][ni][r] + bv;
                if (RELU) v = fmaxf(v, 0.0f);
                C[(long)gr * N + gc] = (OUT_T)v;
            }
        }
    }
}

// ---------------------------------------------------------------------------
__global__ __launch_bounds__(256)
void cast_f32_f16(const float* __restrict__ X, f16* __restrict__ Y)
{
    const long i = ((long)blockIdx.x * 256 + threadIdx.x) * 8;
    float4 a = *(const float4*)(X + i);
    float4 b = *(const float4*)(X + i + 4);
    f16x8 h = {(f16)a.x, (f16)a.y, (f16)a.z, (f16)a.w,
               (f16)b.x, (f16)b.y, (f16)b.z, (f16)b.w};
    *(f16x8*)(Y + i) = h;
}

// proj_q fp32 [2048 x 1024] per batch -> qB fp16 (row-major) AND qBt fp16 [1024 x 2048]
__global__ __launch_bounds__(256)
void cast_q_dual(const float* __restrict__ X, f16* __restrict__ Yrow,
                 f16* __restrict__ Ytr)
{
    __shared__ f16 t[64][72];
    const float* Xb = X + (long)blockIdx.z * (2048L * 1024);
    f16* Yrb = Yrow + (long)blockIdx.z * (2048L * 1024);
    f16* Ytb = Ytr  + (long)blockIdx.z * (1024L * 2048);
    const int r0 = blockIdx.y * 64;
    const int c0 = blockIdx.x * 64;
    const int tid = threadIdx.x;
    const int tr = tid >> 4;
    const int tc = (tid & 15) * 4;
#pragma unroll
    for (int rr = 0; rr < 64; rr += 16) {
        float4 v = *(const float4*)(Xb + (long)(r0 + tr + rr) * 1024 + c0 + tc);
        f16x4 h = {(f16)v.x, (f16)v.y, (f16)v.z, (f16)v.w};
        *(f16x4*)&t[tr + rr][tc] = h;
        *(f16x4*)(Yrb + (long)(r0 + tr + rr) * 1024 + c0 + tc) = h;
    }
    __syncthreads();
#pragma unroll
    for (int rr = 0; rr < 64; rr += 16) {
        const int orow = tr + rr;
        f16x4 o = {t[tc + 0][orow], t[tc + 1][orow], t[tc + 2][orow], t[tc + 3][orow]};
        *(f16x4*)(Ytb + (long)(c0 + orow) * 2048 + r0 + tc) = o;
    }
}

// rowwise softmax over 2048 fp32 -> fp16
__global__ __launch_bounds__(256)
void softmax_p(const float* __restrict__ S, f16* __restrict__ P)
{
    const long row = blockIdx.x;
    const float* s = S + row * 2048;
    f16* p = P + row * 2048;
    const int tid = threadIdx.x;
    const int wid = tid >> 6, lane = tid & 63;

    float4 a = *(const float4*)(s + tid * 8);
    float4 b = *(const float4*)(s + tid * 8 + 4);
    float v[8] = {a.x, a.y, a.z, a.w, b.x, b.y, b.z, b.w};

    float m = v[0];
#pragma unroll
    for (int j = 1; j < 8; ++j) m = fmaxf(m, v[j]);
#pragma unroll
    for (int off = 32; off > 0; off >>= 1) m = fmaxf(m, __shfl_xor(m, off, 64));

    __shared__ float red[8];
    if (lane == 0) red[wid] = m;
    __syncthreads();
    m = fmaxf(fmaxf(red[0], red[1]), fmaxf(red[2], red[3]));

    float sum = 0.f;
#pragma unroll
    for (int j = 0; j < 8; ++j) { v[j] = __expf(v[j] - m); sum += v[j]; }
#pragma unroll
    for (int off = 32; off > 0; off >>= 1) sum += __shfl_xor(sum, off, 64);
    if (lane == 0) red[4 + wid] = sum;
    __syncthreads();
    sum = red[4] + red[5] + red[6] + red[7];

    const float inv = 1.0f / sum;
    f16x8 h = {(f16)(v[0] * inv), (f16)(v[1] * inv), (f16)(v[2] * inv), (f16)(v[3] * inv),
               (f16)(v[4] * inv), (f16)(v[5] * inv), (f16)(v[6] * inv), (f16)(v[7] * inv)};
    *(f16x8*)(p + tid * 8) = h;
}

// ---------------------------------------------------------------------------
extern "C" void kernel_launch(void* const* d_in, const int* in_sizes, int n_in,
                              void* d_out, int out_size, void* d_ws, size_t ws_size,
                              hipStream_t stream)
{
    const float* proj_p = (const float*)d_in[0];  // [16,2048,1024]
    const float* proj_q = (const float*)d_in[1];  // [16,2048,1024]
    const float* W      = (const float*)d_in[2];  // [1024,1024]
    const float* bias   = (const float*)d_in[3];  // [1024]
    float* out = (float*)d_out;

    constexpr long Bc = 16, L = 2048, H = 1024, NB = 4;
    constexpr long nPQ = Bc * L * H;              // 33,554,432 elements

    char* ws = (char*)d_ws;
    f16*   pB  = (f16*)(ws + 0L);                 // 67,108,864 B
    f16*   qB  = (f16*)(ws + 67108864L);          // 67,108,864 B
    f16*   qBt = (f16*)(ws + 134217728L);         // 67,108,864 B  [B][H][L]
    f16*   tQ  = (f16*)(ws + 201326592L);         // 67,108,864 B
    f16*   aV  = (f16*)(ws + 268435456L);         // 67,108,864 B
    f16*   Wb  = (f16*)(ws + 335544320L);         //  2,097,152 B
    float* S   = (float*)(ws + 337641472L);       // 67,108,864 B (4 batches fp32)
    f16*   P   = (f16*)(ws + 404750336L);         // 33,554,432 B (4 batches fp16)
    // total ws use: 438,304,768 B

    cast_f32_f16<<<nPQ / (256 * 8), 256, 0, stream>>>(proj_p, pB);
    cast_f32_f16<<<(H * H) / (256 * 8), 256, 0, stream>>>(W, Wb);
    cast_q_dual<<<dim3(16, 32, 16), 256, 0, stream>>>(proj_q, qB, qBt);

    // G1: tQ[b,q,o] = qB[b,q,:] . Wb[o,:] + bias[o]
    gemm_bt<f16, true, false><<<dim3(H / 128, (Bc * L) / 128, 1), 256, 0, stream>>>(
        qB, Wb, tQ, bias, (int)(Bc * L), (int)H, (int)H, 0, 0, 0);

    for (int c = 0; c < 4; ++c) {
        const long boff = (long)c * NB * L * H;
        // G2: S[p,q] = pB[p,:] . tQ[q,:]   (fp32 out)
        gemm_bt<float, false, false><<<dim3(L / 128, L / 128, NB), 256, 0, stream>>>(
            pB + boff, tQ + boff, S, nullptr, (int)L, (int)L, (int)H,
            L * H, L * H, L * L);
        // softmax rows -> P fp16
        softmax_p<<<NB * L, 256, 0, stream>>>(S, P);
        // G3: aV[p,h] = P[p,:] . qBt[h,:]
        gemm_bt<f16, false, false><<<dim3(H / 128, L / 128, NB), 256, 0, stream>>>(
            P, qBt + (long)c * NB * H * L, aV + boff, nullptr, (int)L, (int)H, (int)L,
            L * L, H * L, L * H);
    }

    // G4: out = relu(aV . Wb^T + bias)  (fp32 out)
    gemm_bt<float, false, true><<<dim3(H / 128, (Bc * L) / 128, 1), 256, 0, stream>>>(
        aV, Wb, out, bias, (int)(Bc * L), (int)H, (int)H, 0, 0, 0);
}